// Round 12
// baseline (102.075 us; speedup 1.0000x reference)
//
#include <hip/hip_runtime.h>

typedef float f32x4 __attribute__((ext_vector_type(4)));

static constexpr int B  = 32;
static constexpr int Q  = 900;   // queries (and pseudo targets Qb)
static constexpr int NC = 91;    // classes
static constexpr int T  = 30;    // gt targets

static constexpr float ALPHA_ = 0.25f;
static constexpr float EPS_   = 1e-8f;
static constexpr float BIG_   = 1e9f;

// ---------------------------------------------------------------------------
// K1: one 64-lane wave per (b, qb) of the base model. Coalesced logit read +
// butterfly argmax; one gt target per lane for the keep-mask.
// Mask is correctness-critical: exact IEEE fp32, no contraction, reference
// op order. (Byte-identical to the passing round-11 version.)
// ---------------------------------------------------------------------------
__global__ __launch_bounds__(256) void k1_mask_label(
    const float* __restrict__ logits_base,
    const float4* __restrict__ boxes_base,
    const float4* __restrict__ targets,
    int* __restrict__ labels,
    float* __restrict__ mask_out) {
#pragma clang fp contract(off)
  int wid  = (blockIdx.x * 256 + threadIdx.x) >> 6;
  int lane = threadIdx.x & 63;
  int b = wid / Q;

  const float* row = logits_base + (size_t)wid * NC;
  float v  = (lane < NC) ? row[lane] : -1e30f;
  int  arg = lane;
  int lane2 = lane + 64;
  if (lane2 < NC) {
    float v2 = row[lane2];
    if (v2 > v) { v = v2; arg = lane2; }   // strict >: keep lower idx on tie
  }
  for (int off = 32; off >= 1; off >>= 1) {
    float ov = __shfl_xor(v, off, 64);
    int   oi = __shfl_xor(arg, off, 64);
    if (ov > v || (ov == v && oi < arg)) { v = ov; arg = oi; }
  }
  bool keep = (v > 0.0f);  // sigmoid(max) > 0.5  <=>  max logit > 0

  float4 bb = boxes_base[wid];
  float x1 = bb.x - 0.5f * bb.z, y1 = bb.y - 0.5f * bb.w;
  float x2 = bb.x + 0.5f * bb.z, y2 = bb.y + 0.5f * bb.w;
  float a1 = (x2 - x1) * (y2 - y1);

  bool ok = true;
  if (lane < T) {
    float4 tb = targets[b * T + lane];
    float tx1 = tb.x - 0.5f * tb.z, ty1 = tb.y - 0.5f * tb.w;
    float tx2 = tb.x + 0.5f * tb.z, ty2 = tb.y + 0.5f * tb.w;
    float a2 = (tx2 - tx1) * (ty2 - ty1);
    float ltx = fmaxf(x1, tx1), lty = fmaxf(y1, ty1);
    float rbx = fminf(x2, tx2), rby = fminf(y2, ty2);
    float iw = fmaxf(rbx - ltx, 0.0f), ih = fmaxf(rby - lty, 0.0f);
    float inter = iw * ih;
    float uni = (a1 + a2) - inter;           // reference grouping
    float iou = inter / uni;                 // IEEE divide
    float cx1 = fminf(x1, tx1), cy1 = fminf(y1, ty1);
    float cx2 = fmaxf(x2, tx2), cy2 = fmaxf(y2, ty2);
    float cw = fmaxf(cx2 - cx1, 0.0f), ch = fmaxf(cy2 - cy1, 0.0f);
    float ac = cw * ch;
    float g = iou - (ac - uni) / ac;
    ok = (-g > -0.1f);                       // all(-g > bbox_thresh)
  }
  keep = keep && __all(ok);

  if (lane == 0) {
    labels[wid]   = arg;
    mask_out[wid] = keep ? 1.0f : 0.0f;
  }
}

// focal-style class cost for one logit (tolerance 2e7: fast intrinsics fine)
__device__ __forceinline__ float class_cost(float x) {
  float p   = __builtin_amdgcn_rcpf(1.0f + __expf(-x));
  float omp = 1.0f - p;
  float pos = ALPHA_ * (omp * omp) * (-__logf(p + EPS_));
  float neg = (1.0f - ALPHA_) * (p * p) * (-__logf(omp + EPS_));
  return pos - neg;
}

// ---------------------------------------------------------------------------
// K3 (wave-independent, MEASUREMENT BUILD: chunk loop repeated 3x,
// idempotent). rep 2-3 re-execute all loads+VALU+stores (asm-zero blocks
// cross-rep CSE). Delta vs round-11 dur = 2x k3; tripled dur cracks the
// rocprof top-5 so k3's steady-state counters become visible.
// ---------------------------------------------------------------------------
__global__ __launch_bounds__(256) void k3_wave(
    const float* __restrict__ pred_logits,
    const float4* __restrict__ pred_boxes,
    const float4* __restrict__ boxes_base,
    const int* __restrict__ labels,
    const float* __restrict__ mask_in,
    float* __restrict__ Cout) {
  __shared__ float s_cc[4][4 * 92];  // [wave][row*92 + class], 5.9 KB

  int tid  = threadIdx.x;
  int lane = tid & 63;
  int wv   = tid >> 6;
  int gwid = blockIdx.x * 4 + wv;       // 0..7199
  int b    = gwid / 225;
  int row0 = (gwid % 225) * 4;          // first of this wave's 4 q-rows

  // ---- stage class costs for 4 rows (364 floats = 91 float4) ----
  const f32x4* lg4 = reinterpret_cast<const f32x4*>(
      pred_logits + ((size_t)(b * Q + row0)) * NC);
  float* sl = s_cc[wv];
  for (int i = lane; i < 91; i += 64) {
    f32x4 v = lg4[i];
#pragma unroll
    for (int e = 0; e < 4; ++e) {
      int f = 4 * i + e;
      int r = f / 91;
      int c = f - r * 91;
      sl[r * 92 + c] = class_cost(v[e]);
    }
  }

  // ---- row constants (wave-uniform) ----
  float4 pe[4], pm[4];
  float  pa[4];
#pragma unroll
  for (int r = 0; r < 4; ++r) {
    float4 pb = pred_boxes[b * Q + row0 + r];
    float px1 = pb.x - 0.5f * pb.z, py1 = pb.y - 0.5f * pb.w;
    float px2 = pb.x + 0.5f * pb.z, py2 = pb.y + 0.5f * pb.w;
    pe[r] = make_float4(px1, py1, px2, py2);
    pm[r] = make_float4(px1 + px2, py1 + py2, pb.z, pb.w);
    pa[r] = (px2 - px1) * (py2 - py1);
  }

  __syncthreads();  // publish LDS

  // ==== measurement: repeat the chunk loop 3x (idempotent) ====
#pragma unroll 1
  for (int rep = 0; rep < 3; ++rep) {
    int zero;
    asm volatile("v_mov_b32 %0, 0" : "=v"(zero));  // defeat cross-rep CSE/LICM
    for (int ch = 0; ch < 4; ++ch) {
      int qb0 = 256 * ch + 4 * lane + zero;
      if (qb0 < Q) {
        int jb = b * Q + qb0;
        int4   lbv = *reinterpret_cast<const int4*>(labels + jb);
        float4 mkv = *reinterpret_cast<const float4*>(mask_in + jb);
        const float* pk[4];
        pk[0] = sl + lbv.x; pk[1] = sl + lbv.y;
        pk[2] = sl + lbv.z; pk[3] = sl + lbv.w;
        float c2big[4];
        c2big[0] = 2.0f + (mkv.x != 0.0f ? 0.0f : BIG_);
        c2big[1] = 2.0f + (mkv.y != 0.0f ? 0.0f : BIG_);
        c2big[2] = 2.0f + (mkv.z != 0.0f ? 0.0f : BIG_);
        c2big[3] = 2.0f + (mkv.w != 0.0f ? 0.0f : BIG_);
        float x1b[4], y1b[4], x2b[4], y2b[4], wb[4], hb[4];
#pragma unroll
        for (int k = 0; k < 4; ++k) {
          float4 bb = boxes_base[jb + k];
          x1b[k] = bb.x - 0.5f * bb.z; y1b[k] = bb.y - 0.5f * bb.w;
          x2b[k] = bb.x + 0.5f * bb.z; y2b[k] = bb.y + 0.5f * bb.w;
          wb[k]  = bb.z; hb[k] = bb.w;
        }
        size_t rowbase = ((size_t)(b * Q + row0)) * Q + qb0;
#pragma unroll
        for (int r = 0; r < 4; ++r, rowbase += Q) {
          float res[4];
#pragma unroll
          for (int k = 0; k < 4; ++k) {
            float cls = pk[k][r * 92];
            float dx = pm[r].x - (x1b[k] + x2b[k]);
            float dy = pm[r].y - (y1b[k] + y2b[k]);
            float dw = pm[r].z - wb[k];
            float dh = pm[r].w - hb[k];
            float l1 = fmaf(0.5f, fabsf(dx) + fabsf(dy), fabsf(dw) + fabsf(dh));
            float mwx = fminf(pe[r].z, x2b[k]) - fmaxf(pe[r].x, x1b[k]);
            float mwy = fminf(pe[r].w, y2b[k]) - fmaxf(pe[r].y, y1b[k]);
            float inter = fmaxf(mwx, 0.0f) * fmaxf(mwy, 0.0f);
            float uni = fmaf(wb[k], hb[k], pa[r]) - inter;
            float cw = (pm[r].z + wb[k]) - mwx;
            float chh = (pm[r].w + hb[k]) - mwy;
            float acl = cw * chh;
            float rr = __builtin_amdgcn_rcpf(uni * acl);
            float t = fmaf(inter, acl, uni * uni) * rr;
            res[k] = fmaf(-2.0f, t, fmaf(5.0f, l1, fmaf(2.0f, cls, c2big[k])));
          }
          *reinterpret_cast<float4*>(Cout + rowbase) =
              make_float4(res[0], res[1], res[2], res[3]);
        }
      }
    }
  }
}

extern "C" void kernel_launch(void* const* d_in, const int* in_sizes, int n_in,
                              void* d_out, int out_size, void* d_ws, size_t ws_size,
                              hipStream_t stream) {
  const float*  pred_logits      = (const float*)d_in[0];
  const float4* pred_boxes       = (const float4*)d_in[1];
  const float*  pred_logits_base = (const float*)d_in[2];
  const float4* pred_boxes_base  = (const float4*)d_in[3];
  const float4* targets          = (const float4*)d_in[4];

  float* out      = (float*)d_out;
  float* mask_out = out + (size_t)B * Q * Q;  // output 1, after C

  int* labels = (int*)d_ws;  // 28800 ints

  k1_mask_label<<<(B * Q) / 4, 256, 0, stream>>>(
      pred_logits_base, pred_boxes_base, targets, labels, mask_out);

  k3_wave<<<1800, 256, 0, stream>>>(
      pred_logits, pred_boxes, pred_boxes_base, labels, mask_out, out);
}

// Round 13
// 52.411 us; speedup vs baseline: 1.9476x; 1.9476x over previous
//
#include <hip/hip_runtime.h>

typedef float f32x4 __attribute__((ext_vector_type(4)));

static constexpr int B  = 32;
static constexpr int Q  = 900;   // queries (and pseudo targets Qb)
static constexpr int NC = 91;    // classes
static constexpr int T  = 30;    // gt targets

static constexpr float ALPHA_ = 0.25f;
static constexpr float EPS_   = 1e-8f;
static constexpr float BIG_   = 1e9f;

// ---------------------------------------------------------------------------
// K1: one 64-lane wave per (b, qb) of the base model. Coalesced logit read +
// butterfly argmax; one gt target per lane for the keep-mask.
// Mask path is correctness-critical: exact IEEE fp32, no contraction,
// reference op order (byte-identical to passing R8-R12 versions).
// NEW: lane 0 also writes the packed per-column struct for k3 (corners,
// w/h/area, c2big) -- k3's per-column VALU prep collapses to ~2 adds.
// ---------------------------------------------------------------------------
__global__ __launch_bounds__(256) void k1_mask_label(
    const float* __restrict__ logits_base,
    const float4* __restrict__ boxes_base,
    const float4* __restrict__ targets,
    int* __restrict__ labels,
    float* __restrict__ mask_out,
    float4* __restrict__ colA,
    float4* __restrict__ colB) {
#pragma clang fp contract(off)
  int wid  = (blockIdx.x * 256 + threadIdx.x) >> 6;
  int lane = threadIdx.x & 63;
  int b = wid / Q;

  const float* row = logits_base + (size_t)wid * NC;
  float v  = (lane < NC) ? row[lane] : -1e30f;
  int  arg = lane;
  int lane2 = lane + 64;
  if (lane2 < NC) {
    float v2 = row[lane2];
    if (v2 > v) { v = v2; arg = lane2; }   // strict >: keep lower idx on tie
  }
  for (int off = 32; off >= 1; off >>= 1) {
    float ov = __shfl_xor(v, off, 64);
    int   oi = __shfl_xor(arg, off, 64);
    if (ov > v || (ov == v && oi < arg)) { v = ov; arg = oi; }
  }
  bool keep = (v > 0.0f);  // sigmoid(max) > 0.5  <=>  max logit > 0

  float4 bb = boxes_base[wid];
  float x1 = bb.x - 0.5f * bb.z, y1 = bb.y - 0.5f * bb.w;
  float x2 = bb.x + 0.5f * bb.z, y2 = bb.y + 0.5f * bb.w;
  float a1 = (x2 - x1) * (y2 - y1);

  bool ok = true;
  if (lane < T) {
    float4 tb = targets[b * T + lane];
    float tx1 = tb.x - 0.5f * tb.z, ty1 = tb.y - 0.5f * tb.w;
    float tx2 = tb.x + 0.5f * tb.z, ty2 = tb.y + 0.5f * tb.w;
    float a2 = (tx2 - tx1) * (ty2 - ty1);
    float ltx = fmaxf(x1, tx1), lty = fmaxf(y1, ty1);
    float rbx = fminf(x2, tx2), rby = fminf(y2, ty2);
    float iw = fmaxf(rbx - ltx, 0.0f), ih = fmaxf(rby - lty, 0.0f);
    float inter = iw * ih;
    float uni = (a1 + a2) - inter;           // reference grouping
    float iou = inter / uni;                 // IEEE divide
    float cx1 = fminf(x1, tx1), cy1 = fminf(y1, ty1);
    float cx2 = fmaxf(x2, tx2), cy2 = fmaxf(y2, ty2);
    float cw = fmaxf(cx2 - cx1, 0.0f), ch = fmaxf(cy2 - cy1, 0.0f);
    float ac = cw * ch;
    float g = iou - (ac - uni) / ac;
    ok = (-g > -0.1f);                       // all(-g > bbox_thresh)
  }
  keep = keep && __all(ok);

  if (lane == 0) {
    labels[wid]   = arg;
    mask_out[wid] = keep ? 1.0f : 0.0f;
    colA[wid] = make_float4(x1, y1, x2, y2);
    colB[wid] = make_float4(bb.z, bb.w, a1, 2.0f + (keep ? 0.0f : BIG_));
  }
}

// focal-style class cost for one logit (tolerance 2e7: fast intrinsics fine)
__device__ __forceinline__ float class_cost(float x) {
  float p   = __builtin_amdgcn_rcpf(1.0f + __expf(-x));
  float omp = 1.0f - p;
  float pos = ALPHA_ * (omp * omp) * (-__logf(p + EPS_));
  float neg = (1.0f - ALPHA_) * (p * p) * (-__logf(omp + EPS_));
  return pos - neg;
}

// ---------------------------------------------------------------------------
// K3 (wave-independent): each WAVE owns one (b, 4 q-rows) tile; columns in 4
// chunks of 256, lane owns 4 consecutive qb -> one float4 store per row per
// chunk. Column state now PRELOADED (colA/colB from k1): per-column prep is
// 2 float4 loads + 2 adds instead of ~12 VALU ops.
// ---------------------------------------------------------------------------
__global__ __launch_bounds__(256) void k3_wave(
    const float* __restrict__ pred_logits,
    const float4* __restrict__ pred_boxes,
    const float4* __restrict__ colA,
    const float4* __restrict__ colB,
    const int* __restrict__ labels,
    float* __restrict__ Cout) {
  __shared__ float s_cc[4][4 * 92];  // [wave][row*92 + class], 5.9 KB

  int tid  = threadIdx.x;
  int lane = tid & 63;
  int wv   = tid >> 6;
  int gwid = blockIdx.x * 4 + wv;       // 0..7199
  int b    = gwid / 225;
  int row0 = (gwid % 225) * 4;          // first of this wave's 4 q-rows

  // ---- stage class costs for 4 rows (364 floats = 91 float4) ----
  const f32x4* lg4 = reinterpret_cast<const f32x4*>(
      pred_logits + ((size_t)(b * Q + row0)) * NC);
  float* sl = s_cc[wv];
  for (int i = lane; i < 91; i += 64) {
    f32x4 v = lg4[i];
#pragma unroll
    for (int e = 0; e < 4; ++e) {
      int f = 4 * i + e;
      int r = f / 91;
      int c = f - r * 91;
      sl[r * 92 + c] = class_cost(v[e]);
    }
  }

  // ---- row constants (wave-uniform) ----
  float4 pe[4], pm[4];
  float  pa[4];
#pragma unroll
  for (int r = 0; r < 4; ++r) {
    float4 pb = pred_boxes[b * Q + row0 + r];
    float px1 = pb.x - 0.5f * pb.z, py1 = pb.y - 0.5f * pb.w;
    float px2 = pb.x + 0.5f * pb.z, py2 = pb.y + 0.5f * pb.w;
    pe[r] = make_float4(px1, py1, px2, py2);
    pm[r] = make_float4(px1 + px2, py1 + py2, pb.z, pb.w);
    pa[r] = (px2 - px1) * (py2 - py1);
  }

  __syncthreads();  // publish LDS

  for (int ch = 0; ch < 4; ++ch) {
    int qb0 = 256 * ch + 4 * lane;
    if (qb0 < Q) {
      int jb = b * Q + qb0;
      int4 lbv = *reinterpret_cast<const int4*>(labels + jb);
      const float* pk[4];
      pk[0] = sl + lbv.x; pk[1] = sl + lbv.y;
      pk[2] = sl + lbv.z; pk[3] = sl + lbv.w;
      float x1b[4], y1b[4], x2b[4], y2b[4], sxb[4], syb[4];
      float wb[4], hb[4], ab[4], c2big[4];
#pragma unroll
      for (int k = 0; k < 4; ++k) {
        float4 ca = colA[jb + k];
        float4 cb = colB[jb + k];
        x1b[k] = ca.x; y1b[k] = ca.y; x2b[k] = ca.z; y2b[k] = ca.w;
        sxb[k] = ca.x + ca.z; syb[k] = ca.y + ca.w;
        wb[k] = cb.x; hb[k] = cb.y; ab[k] = cb.z; c2big[k] = cb.w;
      }
      size_t rowbase = ((size_t)(b * Q + row0)) * Q + qb0;
#pragma unroll
      for (int r = 0; r < 4; ++r, rowbase += Q) {
        float res[4];
#pragma unroll
        for (int k = 0; k < 4; ++k) {
          float cls = pk[k][r * 92];  // ds_read, immediate offset r*368
          float dx = pm[r].x - sxb[k];
          float dy = pm[r].y - syb[k];
          float dw = pm[r].z - wb[k];
          float dh = pm[r].w - hb[k];
          float l1 = fmaf(0.5f, fabsf(dx) + fabsf(dy), fabsf(dw) + fabsf(dh));
          float mwx = fminf(pe[r].z, x2b[k]) - fmaxf(pe[r].x, x1b[k]);
          float mwy = fminf(pe[r].w, y2b[k]) - fmaxf(pe[r].y, y1b[k]);
          float inter = fmaxf(mwx, 0.0f) * fmaxf(mwy, 0.0f);
          float uni = (pa[r] + ab[k]) - inter;
          float cw = (pm[r].z + wb[k]) - mwx;
          float chh = (pm[r].w + hb[k]) - mwy;
          float acl = cw * chh;
          float rr = __builtin_amdgcn_rcpf(uni * acl);
          float t = fmaf(inter, acl, uni * uni) * rr;
          res[k] = fmaf(-2.0f, t, fmaf(5.0f, l1, fmaf(2.0f, cls, c2big[k])));
        }
        *reinterpret_cast<float4*>(Cout + rowbase) =
            make_float4(res[0], res[1], res[2], res[3]);
      }
    }
  }
}

extern "C" void kernel_launch(void* const* d_in, const int* in_sizes, int n_in,
                              void* d_out, int out_size, void* d_ws, size_t ws_size,
                              hipStream_t stream) {
  const float*  pred_logits      = (const float*)d_in[0];
  const float4* pred_boxes       = (const float4*)d_in[1];
  const float*  pred_logits_base = (const float*)d_in[2];
  const float4* pred_boxes_base  = (const float4*)d_in[3];
  const float4* targets          = (const float4*)d_in[4];

  float* out      = (float*)d_out;
  float* mask_out = out + (size_t)B * Q * Q;  // output 1, after C

  int*    labels = (int*)d_ws;                         // 28800 ints
  float4* colA   = (float4*)((char*)d_ws + 131072);    // 28800 float4
  float4* colB   = (float4*)((char*)d_ws + 131072 + 460800);

  k1_mask_label<<<(B * Q) / 4, 256, 0, stream>>>(
      pred_logits_base, pred_boxes_base, targets, labels, mask_out,
      colA, colB);

  k3_wave<<<1800, 256, 0, stream>>>(
      pred_logits, pred_boxes, colA, colB, labels, out);
}